// Round 1
// baseline (536.041 us; speedup 1.0000x reference)
//
#include <hip/hip_runtime.h>
#include <hip/hip_bf16.h>

#define D_IN   128
#define D_OUT  64
#define TILE_R 16

// ---------------------------------------------------------------------------
// Kernel 1: data = h @ W^T + b ; s = data @ a_src ; t = data @ a_dst
// Block = 256 threads: lane c (0..63) owns output column c, 4 waves cover 16 rows.
// ---------------------------------------------------------------------------
__global__ __launch_bounds__(256) void proj_kernel(
    const float* __restrict__ h, const float* __restrict__ Ww,
    const float* __restrict__ Wb, const float* __restrict__ a,
    float* __restrict__ data, float* __restrict__ s_out, float* __restrict__ t_out,
    int n)
{
    __shared__ float wt[D_IN][D_OUT + 1];   // transposed W, +1 pad vs bank conflicts
    __shared__ float hs[TILE_R][D_IN];

    const int tid = threadIdx.x;

    // Load W transposed into LDS (8192 elements, 32 per thread)
    for (int i = tid; i < D_OUT * D_IN; i += 256) {
        int c = i >> 7;          // row of W  (output col)
        int k = i & (D_IN - 1);  // col of W  (input dim)
        wt[k][c] = Ww[i];
    }

    // Stage 16 rows of h
    const int r0 = blockIdx.x * TILE_R;
    for (int i = tid; i < TILE_R * D_IN; i += 256) {
        int r = i >> 7;
        int k = i & (D_IN - 1);
        hs[r][k] = (r0 + r < n) ? h[(size_t)(r0 + r) * D_IN + k] : 0.0f;
    }
    __syncthreads();

    const int c    = tid & 63;
    const int wave = tid >> 6;
    const float a_src_c = a[c];
    const float a_dst_c = a[D_OUT + c];
    const float bias_c  = Wb[c];

    for (int rl = wave; rl < TILE_R; rl += 4) {
        float acc = 0.0f;
        #pragma unroll
        for (int k = 0; k < D_IN; ++k)
            acc = fmaf(hs[rl][k], wt[k][c], acc);
        acc += bias_c;

        const int r = r0 + rl;
        if (r < n) data[(size_t)r * D_OUT + c] = acc;

        // wave-wide reductions for s and t
        float sp = acc * a_src_c;
        float tp = acc * a_dst_c;
        #pragma unroll
        for (int off = 32; off > 0; off >>= 1) {
            sp += __shfl_xor(sp, off);
            tp += __shfl_xor(tp, off);
        }
        if (c == 0 && r < n) { s_out[r] = sp; t_out[r] = tp; }
    }
}

// ---------------------------------------------------------------------------
// Kernel 2: one wave per edge. Lane i handles feature i.
// ---------------------------------------------------------------------------
__global__ __launch_bounds__(256) void edge_kernel(
    const int* __restrict__ e0a, const int* __restrict__ e1a,
    const float* __restrict__ s, const float* __restrict__ t,
    const float* __restrict__ data,
    float* __restrict__ agg, float* __restrict__ rowsum, int nedges)
{
    const int wid  = (int)((blockIdx.x * (size_t)blockDim.x + threadIdx.x) >> 6);
    const int lane = threadIdx.x & 63;
    if (wid >= nedges) return;

    const int e0 = e0a[wid];
    const int e1 = e1a[wid];

    const float raw = s[e0] + t[e1];
    const float lr  = raw > 0.0f ? raw : 0.2f * raw;
    const float w   = __expf(lr * 0.125f);   // 1/sqrt(64) = 0.125

    const float v = w * data[(size_t)e1 * D_OUT + lane];
    atomicAdd(&agg[(size_t)e0 * D_OUT + lane], v);
    if (lane == 0) atomicAdd(&rowsum[e0], w);
}

// ---------------------------------------------------------------------------
// Kernel 3: finalize — empty rows pass through data, others divide by rowsum
// ---------------------------------------------------------------------------
__global__ __launch_bounds__(256) void finalize_kernel(
    const float* __restrict__ data, const float* __restrict__ rowsum,
    float* __restrict__ out, int n)
{
    const size_t i = blockIdx.x * (size_t)blockDim.x + threadIdx.x;
    if (i >= (size_t)n * D_OUT) return;
    const int node = (int)(i >> 6);
    const float rs = rowsum[node];
    out[i] = (rs == 0.0f) ? data[i] : out[i] / rs;
}

extern "C" void kernel_launch(void* const* d_in, const int* in_sizes, int n_in,
                              void* d_out, int out_size, void* d_ws, size_t ws_size,
                              hipStream_t stream)
{
    const float* h    = (const float*)d_in[0];
    const int*   edge = (const int*)d_in[1];   // int32 on device (jax x64 off)
    const float* Ww   = (const float*)d_in[2];
    const float* Wb   = (const float*)d_in[3];
    const float* a    = (const float*)d_in[4];

    const int n  = in_sizes[0] / D_IN;       // 100000
    const int ne = in_sizes[1] / 2;          // 1600000

    const int* e0a = edge;
    const int* e1a = edge + ne;

    float* out  = (float*)d_out;
    float* ws   = (float*)d_ws;
    float* data = ws;                                  // n*64 floats
    float* s    = data + (size_t)n * D_OUT;            // n floats
    float* t    = s + n;                               // n floats
    float* rsum = t + n;                               // n floats

    hipMemsetAsync(d_out, 0, (size_t)n * D_OUT * sizeof(float), stream);
    hipMemsetAsync(rsum, 0, (size_t)n * sizeof(float), stream);

    proj_kernel<<<(n + TILE_R - 1) / TILE_R, 256, 0, stream>>>(
        h, Ww, Wb, a, data, s, t, n);

    const size_t edge_threads = (size_t)ne * 64;
    edge_kernel<<<(int)((edge_threads + 255) / 256), 256, 0, stream>>>(
        e0a, e1a, s, t, data, out, rsum, ne);

    finalize_kernel<<<(int)(((size_t)n * D_OUT + 255) / 256), 256, 0, stream>>>(
        data, rsum, out, n);
}

// Round 2
// 375.667 us; speedup vs baseline: 1.4269x; 1.4269x over previous
//
#include <hip/hip_runtime.h>
#include <hip/hip_bf16.h>

#define D_IN   128
#define D_OUT  64
#define TILE_R 16

// ---------------------------------------------------------------------------
// Kernel 1: data = h @ W^T + b ; s = data @ a_src ; t = data @ a_dst
// ---------------------------------------------------------------------------
__global__ __launch_bounds__(256) void proj_kernel(
    const float* __restrict__ h, const float* __restrict__ Ww,
    const float* __restrict__ Wb, const float* __restrict__ a,
    float* __restrict__ data, float* __restrict__ s_out, float* __restrict__ t_out,
    int n)
{
    __shared__ float wt[D_IN][D_OUT + 1];
    __shared__ float hs[TILE_R][D_IN];

    const int tid = threadIdx.x;

    for (int i = tid; i < D_OUT * D_IN; i += 256) {
        int c = i >> 7;
        int k = i & (D_IN - 1);
        wt[k][c] = Ww[i];
    }

    const int r0 = blockIdx.x * TILE_R;
    for (int i = tid; i < TILE_R * D_IN; i += 256) {
        int r = i >> 7;
        int k = i & (D_IN - 1);
        hs[r][k] = (r0 + r < n) ? h[(size_t)(r0 + r) * D_IN + k] : 0.0f;
    }
    __syncthreads();

    const int c    = tid & 63;
    const int wave = tid >> 6;
    const float a_src_c = a[c];
    const float a_dst_c = a[D_OUT + c];
    const float bias_c  = Wb[c];

    for (int rl = wave; rl < TILE_R; rl += 4) {
        float acc = 0.0f;
        #pragma unroll
        for (int k = 0; k < D_IN; ++k)
            acc = fmaf(hs[rl][k], wt[k][c], acc);
        acc += bias_c;

        const int r = r0 + rl;
        if (r < n) data[(size_t)r * D_OUT + c] = acc;

        float sp = acc * a_src_c;
        float tp = acc * a_dst_c;
        #pragma unroll
        for (int off = 32; off > 0; off >>= 1) {
            sp += __shfl_xor(sp, off);
            tp += __shfl_xor(tp, off);
        }
        if (c == 0 && r < n) { s_out[r] = sp; t_out[r] = tp; }
    }
}

// ---------------------------------------------------------------------------
// CSR build: histogram -> exclusive scan (3 stages) -> scatter e1 by e0
// ---------------------------------------------------------------------------
__global__ __launch_bounds__(256) void hist_kernel(
    const int* __restrict__ e0a, int* __restrict__ counts, int ne)
{
    int i = blockIdx.x * 256 + threadIdx.x;
    if (i < ne) atomicAdd(&counts[e0a[i]], 1);
}

// per-block exclusive scan over 1024 counts (256 thr x 4 items)
__global__ __launch_bounds__(256) void scan1_kernel(
    const int* __restrict__ counts, int* __restrict__ offs,
    int* __restrict__ bsums, int n)
{
    __shared__ int wsum[4];
    const int tid  = threadIdx.x;
    const int base = blockIdx.x * 1024 + tid * 4;

    int v0 = (base + 0 < n) ? counts[base + 0] : 0;
    int v1 = (base + 1 < n) ? counts[base + 1] : 0;
    int v2 = (base + 2 < n) ? counts[base + 2] : 0;
    int v3 = (base + 3 < n) ? counts[base + 3] : 0;
    const int tsum = v0 + v1 + v2 + v3;

    int x = tsum;
    #pragma unroll
    for (int off = 1; off < 64; off <<= 1) {
        int y = __shfl_up(x, off);
        if ((tid & 63) >= off) x += y;
    }
    const int wave = tid >> 6;
    if ((tid & 63) == 63) wsum[wave] = x;
    __syncthreads();

    int wofs = 0;
    #pragma unroll
    for (int w = 0; w < 4; ++w) if (w < wave) wofs += wsum[w];
    const int tofs = wofs + x - tsum;

    if (base + 0 < n) offs[base + 0] = tofs;
    if (base + 1 < n) offs[base + 1] = tofs + v0;
    if (base + 2 < n) offs[base + 2] = tofs + v0 + v1;
    if (base + 3 < n) offs[base + 3] = tofs + v0 + v1 + v2;
    if (tid == 0) bsums[blockIdx.x] = wsum[0] + wsum[1] + wsum[2] + wsum[3];
}

// single-block exclusive scan of block sums (nb <= 256)
__global__ __launch_bounds__(256) void scan2_kernel(int* __restrict__ bsums, int nb)
{
    __shared__ int wsum[4];
    const int tid = threadIdx.x;
    const int v = (tid < nb) ? bsums[tid] : 0;
    int x = v;
    #pragma unroll
    for (int off = 1; off < 64; off <<= 1) {
        int y = __shfl_up(x, off);
        if ((tid & 63) >= off) x += y;
    }
    const int wave = tid >> 6;
    if ((tid & 63) == 63) wsum[wave] = x;
    __syncthreads();
    int wofs = 0;
    #pragma unroll
    for (int w = 0; w < 4; ++w) if (w < wave) wofs += wsum[w];
    if (tid < nb) bsums[tid] = wofs + x - v;
}

__global__ __launch_bounds__(256) void scan3_kernel(
    int* __restrict__ offs, const int* __restrict__ bsums,
    int* __restrict__ cursor, int n)
{
    const int b = bsums[blockIdx.x];
    const int base = blockIdx.x * 1024 + threadIdx.x;
    #pragma unroll
    for (int j = 0; j < 4; ++j) {
        int idx = base + j * 256;
        if (idx < n) {
            int o = offs[idx] + b;
            offs[idx] = o;
            cursor[idx] = o;
        }
    }
}

__global__ __launch_bounds__(256) void scatter_kernel(
    const int* __restrict__ e0a, const int* __restrict__ e1a,
    int* __restrict__ cursor, int* __restrict__ se1, int ne)
{
    int i = blockIdx.x * 256 + threadIdx.x;
    if (i < ne) {
        int u = e0a[i];
        int pos = atomicAdd(&cursor[u], 1);
        se1[pos] = e1a[i];
    }
}

// ---------------------------------------------------------------------------
// Node aggregation: one wave per node, lane = feature. No atomics.
// ---------------------------------------------------------------------------
__global__ __launch_bounds__(256) void node_kernel(
    const int* __restrict__ se1, const int* __restrict__ offs,
    const int* __restrict__ counts,
    const float* __restrict__ s, const float* __restrict__ t,
    const float* __restrict__ data, float* __restrict__ out, int n)
{
    const int wave = threadIdx.x >> 6;
    const int lane = threadIdx.x & 63;
    const int u = blockIdx.x * 4 + wave;
    if (u >= n) return;

    const int start = offs[u];
    const int deg   = counts[u];
    const float su  = s[u];

    float acc = 0.0f, wsum = 0.0f;

    int j = 0;
    for (; j + 1 < deg; j += 2) {
        const int v0 = se1[start + j];
        const int v1 = se1[start + j + 1];
        const float d0 = data[(size_t)v0 * D_OUT + lane];
        const float d1 = data[(size_t)v1 * D_OUT + lane];
        const float r0 = su + t[v0];
        const float r1 = su + t[v1];
        const float l0 = r0 > 0.0f ? r0 : 0.2f * r0;
        const float l1 = r1 > 0.0f ? r1 : 0.2f * r1;
        const float w0 = __expf(l0 * 0.125f);
        const float w1 = __expf(l1 * 0.125f);
        wsum += w0 + w1;
        acc = fmaf(w0, d0, acc);
        acc = fmaf(w1, d1, acc);
    }
    if (j < deg) {
        const int v0 = se1[start + j];
        const float d0 = data[(size_t)v0 * D_OUT + lane];
        const float r0 = su + t[v0];
        const float l0 = r0 > 0.0f ? r0 : 0.2f * r0;
        const float w0 = __expf(l0 * 0.125f);
        wsum += w0;
        acc = fmaf(w0, d0, acc);
    }

    float o;
    if (deg == 0) o = data[(size_t)u * D_OUT + lane];
    else          o = acc / wsum;
    out[(size_t)u * D_OUT + lane] = o;
}

extern "C" void kernel_launch(void* const* d_in, const int* in_sizes, int n_in,
                              void* d_out, int out_size, void* d_ws, size_t ws_size,
                              hipStream_t stream)
{
    const float* h    = (const float*)d_in[0];
    const int*   edge = (const int*)d_in[1];
    const float* Ww   = (const float*)d_in[2];
    const float* Wb   = (const float*)d_in[3];
    const float* a    = (const float*)d_in[4];

    const int n  = in_sizes[0] / D_IN;    // 100000
    const int ne = in_sizes[1] / 2;       // 1600000

    const int* e0a = edge;
    const int* e1a = edge + ne;
    float* out = (float*)d_out;

    // workspace layout
    char* wsp = (char*)d_ws;
    float* data   = (float*)wsp;                 wsp += (size_t)n * D_OUT * sizeof(float);
    float* s      = (float*)wsp;                 wsp += (size_t)n * sizeof(float);
    float* t      = (float*)wsp;                 wsp += (size_t)n * sizeof(float);
    int*   counts = (int*)wsp;                   wsp += (size_t)n * sizeof(int);
    int*   offs   = (int*)wsp;                   wsp += (size_t)n * sizeof(int);
    int*   cursor = (int*)wsp;                   wsp += (size_t)n * sizeof(int);
    int*   bsums  = (int*)wsp;                   wsp += 1024 * sizeof(int);
    int*   se1    = (int*)wsp;                   wsp += (size_t)ne * sizeof(int);

    const int nb = (n + 1023) / 1024;            // 98 blocks (<= 256 required)

    hipMemsetAsync(counts, 0, (size_t)n * sizeof(int), stream);

    proj_kernel<<<(n + TILE_R - 1) / TILE_R, 256, 0, stream>>>(
        h, Ww, Wb, a, data, s, t, n);

    hist_kernel<<<(ne + 255) / 256, 256, 0, stream>>>(e0a, counts, ne);
    scan1_kernel<<<nb, 256, 0, stream>>>(counts, offs, bsums, n);
    scan2_kernel<<<1, 256, 0, stream>>>(bsums, nb);
    scan3_kernel<<<nb, 256, 0, stream>>>(offs, bsums, cursor, n);
    scatter_kernel<<<(ne + 255) / 256, 256, 0, stream>>>(e0a, e1a, cursor, se1, ne);

    node_kernel<<<(n + 3) / 4, 256, 0, stream>>>(
        se1, offs, counts, s, t, data, out, n);
}